// Round 1
// baseline (69.777 us; speedup 1.0000x reference)
//
#include <hip/hip_runtime.h>
#include <hip/hip_bf16.h>

typedef _Float16 f16;
typedef _Float16 f16x8 __attribute__((ext_vector_type(8)));
typedef _Float16 f16x4 __attribute__((ext_vector_type(4)));
typedef float f32x4 __attribute__((ext_vector_type(4)));

#define BD 512  // D == H == 512

// async global->LDS, 16B per lane. LDS dest is wave-uniform base + lane*16.
__device__ __forceinline__ void llds16(const f16* g, f16* l) {
  __builtin_amdgcn_global_load_lds(
      (const __attribute__((address_space(1))) unsigned int*)g,
      (__attribute__((address_space(3))) unsigned int*)l,
      16, 0, 0);
}

// ---------------- prep: convert weights + mem to fp16, mem norms, zero accum ----------------
__global__ __launch_bounds__(256) void prep_kernel(
    const float* __restrict__ projW, const float* __restrict__ opsW,
    const float* __restrict__ memf,
    f16* __restrict__ wh,      // [262144 + 786432] : proj_W then ops_W
    f16* __restrict__ memh,    // [64*512] zero-padded
    float* __restrict__ mn2,   // [64]
    float* __restrict__ novS) {
  const int blk = blockIdx.x;
  if (blk < 1024) {
    int i = blk * 256 + threadIdx.x;
    int e = i * 4;
    const float* s = (e < 262144) ? (projW + e) : (opsW + (e - 262144));
    float4 v = *(const float4*)s;
    f16x4 h;
    h[0] = (f16)v.x; h[1] = (f16)v.y; h[2] = (f16)v.z; h[3] = (f16)v.w;
    *(f16x4*)&wh[e] = h;
  } else {
    const int t = threadIdx.x, l = t & 63, w = t >> 6;
    const int row = (blk - 1024) * 4 + w;   // 0..63
    if (blk == 1024 && t == 0) *novS = 0.0f;
    f16x8 h;
    float ss = 0.0f;
    if (row < 50) {
      const float* src = memf + (size_t)row * BD + l * 8;
      float4 v0 = *(const float4*)src;
      float4 v1 = *(const float4*)(src + 4);
      h[0] = (f16)v0.x; h[1] = (f16)v0.y; h[2] = (f16)v0.z; h[3] = (f16)v0.w;
      h[4] = (f16)v1.x; h[5] = (f16)v1.y; h[6] = (f16)v1.z; h[7] = (f16)v1.w;
      ss = v0.x*v0.x + v0.y*v0.y + v0.z*v0.z + v0.w*v0.w
         + v1.x*v1.x + v1.y*v1.y + v1.z*v1.z + v1.w*v1.w;
      #pragma unroll
      for (int off = 32; off; off >>= 1) ss += __shfl_down(ss, off, 64);
    } else {
      #pragma unroll
      for (int j = 0; j < 8; ++j) h[j] = (f16)0.0f;
    }
    *(f16x8*)&memh[(size_t)row * BD + l * 8] = h;
    if (l == 0) mn2[row] = ss;
  }
}

// ---------------- convert x to fp16 + row sum-of-squares ----------------
__global__ __launch_bounds__(256) void convert_x_kernel(
    const float* __restrict__ x, f16* __restrict__ xh, float* __restrict__ xn2) {
  const int t = threadIdx.x, l = t & 63, w = t >> 6;
  const int row = blockIdx.x * 4 + w;
  const float* src = x + (size_t)row * BD + l * 8;
  float4 v0 = *(const float4*)src;
  float4 v1 = *(const float4*)(src + 4);
  f16x8 h;
  h[0] = (f16)v0.x; h[1] = (f16)v0.y; h[2] = (f16)v0.z; h[3] = (f16)v0.w;
  h[4] = (f16)v1.x; h[5] = (f16)v1.y; h[6] = (f16)v1.z; h[7] = (f16)v1.w;
  *(f16x8*)&xh[(size_t)row * BD + l * 8] = h;
  float ss = v0.x*v0.x + v0.y*v0.y + v0.z*v0.z + v0.w*v0.w
           + v1.x*v1.x + v1.y*v1.y + v1.z*v1.z + v1.w*v1.w;
  #pragma unroll
  for (int off = 32; off; off >>= 1) ss += __shfl_down(ss, off, 64);
  if (l == 0) xn2[row] = ss;
}

// ---------------- novelty: dots via MFMA, sum sqrt(||x||^2 - 2 x.m + ||m||^2) ----------------
__global__ __launch_bounds__(256) void novelty_kernel(
    const f16* __restrict__ xh, const f16* __restrict__ memh,
    const float* __restrict__ xn2, const float* __restrict__ mn2,
    float* __restrict__ novS) {
  const int t = threadIdx.x, l = t & 63, w = t >> 6;
  const int lr = l & 15, lk = l >> 4;
  const int r0 = blockIdx.x * 64 + w * 16;

  f32x4 acc[4];
  #pragma unroll
  for (int n = 0; n < 4; ++n) acc[n] = (f32x4){0.f, 0.f, 0.f, 0.f};

  for (int kk = 0; kk < BD; kk += 32) {
    f16x8 a = *(const f16x8*)&xh[(size_t)(r0 + lr) * BD + kk + lk * 8];
    #pragma unroll
    for (int n = 0; n < 4; ++n) {
      f16x8 b = *(const f16x8*)&memh[(size_t)(n * 16 + lr) * BD + kk + lk * 8];
      acc[n] = __builtin_amdgcn_mfma_f32_16x16x32_f16(a, b, acc[n], 0, 0, 0);
    }
  }
  float local = 0.0f;
  #pragma unroll
  for (int n = 0; n < 4; ++n) {
    int mm = n * 16 + lr;              // C/D: col = lane&15
    if (mm < 50) {
      float mn = mn2[mm];
      #pragma unroll
      for (int j = 0; j < 4; ++j) {
        int row = r0 + lk * 4 + j;     // C/D: row = (lane>>4)*4 + j
        float d = xn2[row] - 2.0f * acc[n][j] + mn;
        local += sqrtf(fmaxf(d, 0.0f));
      }
    }
  }
  #pragma unroll
  for (int off = 32; off; off >>= 1) local += __shfl_down(local, off, 64);
  __shared__ float red[4];
  if (l == 0) red[w] = local;
  __syncthreads();
  if (t == 0) atomicAdd(novS, red[0] + red[1] + red[2] + red[3]);
}

__global__ void nov_final_kernel(const float* __restrict__ novS, float* __restrict__ outv) {
  float m = *novS * (1.0f / (8192.0f * 50.0f));
  *outv = fminf(1.5f, m);
}

// ---------------- GEMM: out = relu(A @ W^T + bias), A[M,512] f16, W[512,512] f16 row-major ----------------
// PICK: 0 = use W directly; 1 = ops_W[idx_a]; 2 = ops_W[idx_b]
template <int PICK, int OUTF16>
__global__ __launch_bounds__(256) void gemm_relu_kernel(
    const f16* __restrict__ A, const f16* __restrict__ Wall,
    const float* __restrict__ ball, const float* __restrict__ logits,
    void* __restrict__ Out) {
  __shared__ __align__(16) f16 As[128 * 64];
  __shared__ __align__(16) f16 Bs[128 * 64];

  const int t = threadIdx.x;
  const int l = t & 63;
  const int w = t >> 6;
  const int wr = w >> 1, wc = w & 1;
  const int lr = l & 15, lk = l >> 4;

  int widx = 0;
  if (PICK > 0) {
    float l0 = logits[0], l1 = logits[1], l2 = logits[2];
    int ia = 0; float ba = l0;
    if (l1 > ba) { ba = l1; ia = 1; }
    if (l2 > ba) { ba = l2; ia = 2; }
    if (PICK == 1) {
      widx = ia;
    } else {
      int ib = 0; float bb2 = -3.4e38f;
      if (ia != 0 && l0 > bb2) { bb2 = l0; ib = 0; }
      if (ia != 1 && l1 > bb2) { bb2 = l1; ib = 1; }
      if (ia != 2 && l2 > bb2) { bb2 = l2; ib = 2; }
      widx = ib;
    }
  }
  const f16* W = Wall + (size_t)widx * BD * BD;
  const float* bias = ball + widx * BD;

  const int rowBase = blockIdx.x * 128;
  const int colBase = blockIdx.y * 128;

  f32x4 acc[4][4];
  #pragma unroll
  for (int m = 0; m < 4; ++m)
    #pragma unroll
    for (int n = 0; n < 4; ++n) acc[m][n] = (f32x4){0.f, 0.f, 0.f, 0.f};

  for (int kt = 0; kt < BD; kt += 64) {
    // stage 128x64 fp16 tiles of A and W via global_load_lds (linear LDS dest,
    // XOR-swizzled global source; read side applies the same swizzle)
    #pragma unroll
    for (int i = 0; i < 4; ++i) {
      int o = i * 4096 + w * 1024 + l * 16;   // byte offset in 16 KB tile
      int row = o >> 7;                        // 128 B per row (64 f16)
      int ch = (o >> 4) & 7;
      int sch = ch ^ (row & 7);
      const f16* gA = A + (size_t)(rowBase + row) * BD + kt + sch * 8;
      const f16* gB = W + (size_t)(colBase + row) * BD + kt + sch * 8;
      f16* lA = As + (i * 4096 + w * 1024) / 2;
      f16* lB = Bs + (i * 4096 + w * 1024) / 2;
      llds16(gA, lA);
      llds16(gB, lB);
    }
    __syncthreads();

    #pragma unroll
    for (int kk = 0; kk < 64; kk += 32) {
      f16x8 af[4], bf[4];
      #pragma unroll
      for (int m = 0; m < 4; ++m) {
        int row = wr * 64 + m * 16 + lr;
        int ch = (kk >> 3) + lk;
        af[m] = *(const f16x8*)&As[row * 64 + ((ch ^ (row & 7)) << 3)];
      }
      #pragma unroll
      for (int n = 0; n < 4; ++n) {
        int row = wc * 64 + n * 16 + lr;
        int ch = (kk >> 3) + lk;
        bf[n] = *(const f16x8*)&Bs[row * 64 + ((ch ^ (row & 7)) << 3)];
      }
      #pragma unroll
      for (int m = 0; m < 4; ++m)
        #pragma unroll
        for (int n = 0; n < 4; ++n)
          acc[m][n] = __builtin_amdgcn_mfma_f32_16x16x32_f16(af[m], bf[n], acc[m][n], 0, 0, 0);
    }
    __syncthreads();
  }

  // epilogue: bias + relu, store
  #pragma unroll
  for (int n = 0; n < 4; ++n) {
    int col = colBase + wc * 64 + n * 16 + lr;
    float bb = bias[col];
    #pragma unroll
    for (int m = 0; m < 4; ++m) {
      #pragma unroll
      for (int j = 0; j < 4; ++j) {
        int rowg = rowBase + wr * 64 + m * 16 + lk * 4 + j;
        float v = acc[m][n][j] + bb;
        v = fmaxf(v, 0.0f);
        if (OUTF16)
          ((f16*)Out)[(size_t)rowg * BD + col] = (f16)v;
        else
          ((float*)Out)[(size_t)rowg * BD + col] = v;
      }
    }
  }
}

extern "C" void kernel_launch(void* const* d_in, const int* in_sizes, int n_in,
                              void* d_out, int out_size, void* d_ws, size_t ws_size,
                              hipStream_t stream) {
  const float* x      = (const float*)d_in[0];   // [8192,512]
  const float* memf   = (const float*)d_in[1];   // [50,512]
  const float* logits = (const float*)d_in[2];   // [3]
  const float* projW  = (const float*)d_in[3];   // [512,512]
  const float* projB  = (const float*)d_in[4];   // [512]
  const float* opsW   = (const float*)d_in[5];   // [3,512,512]
  const float* opsB   = (const float*)d_in[6];   // [3,512]
  float* out = (float*)d_out;                    // [8192*512 + 1]

  char* ws = (char*)d_ws;
  f16*   xh   = (f16*)(ws);                  // 8 MB   (reused as h1 after novelty)
  f16*   g0   = (f16*)(ws + 8388608);        // 8 MB
  f16*   wh   = (f16*)(ws + 16777216);       // 2 MB: proj_W fp16, then ops_W fp16
  f16*   memh = (f16*)(ws + 18874368);       // 64 KB (64x512, zero-padded)
  float* xn2  = (float*)(ws + 18939904);     // 32 KB
  float* mn2  = (float*)(ws + 18972672);     // 256 B
  float* novS = (float*)(ws + 18972928);     // 4 B

  prep_kernel<<<1040, 256, 0, stream>>>(projW, opsW, memf, wh, memh, mn2, novS);
  convert_x_kernel<<<2048, 256, 0, stream>>>(x, xh, xn2);
  novelty_kernel<<<128, 256, 0, stream>>>(xh, memh, xn2, mn2, novS);
  nov_final_kernel<<<1, 1, 0, stream>>>(novS, out + 4194304);

  // g0 = relu(x @ projW^T + projB)
  gemm_relu_kernel<0, 1><<<dim3(64, 4), 256, 0, stream>>>(xh, wh, projB, logits, (void*)g0);
  // h1 = relu(g0 @ Wa^T + ba)   (h1 overwrites xh; novelty already consumed xh)
  gemm_relu_kernel<1, 1><<<dim3(64, 4), 256, 0, stream>>>(g0, wh + 262144, opsB, logits, (void*)xh);
  // out = relu(h1 @ Wb^T + bb)
  gemm_relu_kernel<2, 0><<<dim3(64, 4), 256, 0, stream>>>(xh, wh + 262144, opsB, logits, (void*)out);
}

// Round 2
// 49.631 us; speedup vs baseline: 1.4059x; 1.4059x over previous
//
#include <hip/hip_runtime.h>
#include <hip/hip_bf16.h>

typedef _Float16 f16;
typedef _Float16 f16x8 __attribute__((ext_vector_type(8)));
typedef _Float16 f16x4 __attribute__((ext_vector_type(4)));
typedef float f32x4 __attribute__((ext_vector_type(4)));

#define BD 512  // D == H == 512

// async global->LDS, 16B per lane. LDS dest is wave-uniform base + lane*16.
__device__ __forceinline__ void llds16(const f16* g, f16* l) {
  __builtin_amdgcn_global_load_lds(
      (const __attribute__((address_space(1))) unsigned int*)g,
      (__attribute__((address_space(3))) unsigned int*)l,
      16, 0, 0);
}

// ---------------- prep: convert weights + mem to fp16, mem norms, zero accum ----------------
__global__ __launch_bounds__(256) void prep_kernel(
    const float* __restrict__ projW, const float* __restrict__ opsW,
    const float* __restrict__ memf,
    f16* __restrict__ wh,      // [262144 + 786432] : proj_W then ops_W
    f16* __restrict__ memh,    // [64*512] zero-padded
    float* __restrict__ mn2,   // [64]
    float* __restrict__ novS) {
  const int blk = blockIdx.x;
  if (blk < 1024) {
    int i = blk * 256 + threadIdx.x;
    int e = i * 4;
    const float* s = (e < 262144) ? (projW + e) : (opsW + (e - 262144));
    float4 v = *(const float4*)s;
    f16x4 h;
    h[0] = (f16)v.x; h[1] = (f16)v.y; h[2] = (f16)v.z; h[3] = (f16)v.w;
    *(f16x4*)&wh[e] = h;
  } else {
    const int t = threadIdx.x, l = t & 63, w = t >> 6;
    const int row = (blk - 1024) * 4 + w;   // 0..63
    if (blk == 1024 && t == 0) *novS = 0.0f;
    f16x8 h;
    float ss = 0.0f;
    if (row < 50) {
      const float* src = memf + (size_t)row * BD + l * 8;
      float4 v0 = *(const float4*)src;
      float4 v1 = *(const float4*)(src + 4);
      h[0] = (f16)v0.x; h[1] = (f16)v0.y; h[2] = (f16)v0.z; h[3] = (f16)v0.w;
      h[4] = (f16)v1.x; h[5] = (f16)v1.y; h[6] = (f16)v1.z; h[7] = (f16)v1.w;
      ss = v0.x*v0.x + v0.y*v0.y + v0.z*v0.z + v0.w*v0.w
         + v1.x*v1.x + v1.y*v1.y + v1.z*v1.z + v1.w*v1.w;
      #pragma unroll
      for (int off = 32; off; off >>= 1) ss += __shfl_down(ss, off, 64);
    } else {
      #pragma unroll
      for (int j = 0; j < 8; ++j) h[j] = (f16)0.0f;
    }
    *(f16x8*)&memh[(size_t)row * BD + l * 8] = h;
    if (l == 0) mn2[row] = ss;
  }
}

// ---------------- fused: x fp32 -> xh f16 (global+LDS), row norms, novelty MFMA ----------------
__global__ __launch_bounds__(256) void conv_nov_kernel(
    const float* __restrict__ x, const f16* __restrict__ memh,
    const float* __restrict__ mn2, f16* __restrict__ xh,
    float* __restrict__ novS) {
  __shared__ __align__(16) f16 As[32 * BD];   // 32 KB, chunk-swizzled
  __shared__ float xn[32];
  __shared__ float red[4];
  const int t = threadIdx.x, l = t & 63, w = t >> 6;
  const int rbase = blockIdx.x * 32;

  // phase 1: convert rows w*8..w*8+7; lane l covers cols l*8..l*8+7
  #pragma unroll
  for (int rr = 0; rr < 8; ++rr) {
    const int r = w * 8 + rr;
    const float* src = x + (size_t)(rbase + r) * BD + l * 8;
    float4 v0 = *(const float4*)src;
    float4 v1 = *(const float4*)(src + 4);
    f16x8 h;
    h[0] = (f16)v0.x; h[1] = (f16)v0.y; h[2] = (f16)v0.z; h[3] = (f16)v0.w;
    h[4] = (f16)v1.x; h[5] = (f16)v1.y; h[6] = (f16)v1.z; h[7] = (f16)v1.w;
    *(f16x8*)&xh[(size_t)(rbase + r) * BD + l * 8] = h;
    const int cs = l ^ (r & 7);               // chunk swizzle (low 3 bits)
    *(f16x8*)&As[r * BD + cs * 8] = h;
    float ss = v0.x*v0.x + v0.y*v0.y + v0.z*v0.z + v0.w*v0.w
             + v1.x*v1.x + v1.y*v1.y + v1.z*v1.z + v1.w*v1.w;
    #pragma unroll
    for (int off = 32; off; off >>= 1) ss += __shfl_down(ss, off, 64);
    if (l == 0) xn[r] = ss;
  }
  __syncthreads();

  // phase 2: wave w handles mem cols w*16..w*16+15, x rows 0..31
  const int lr = l & 15, lk = l >> 4;
  f32x4 acc[2];
  acc[0] = (f32x4){0.f, 0.f, 0.f, 0.f};
  acc[1] = (f32x4){0.f, 0.f, 0.f, 0.f};
  #pragma unroll
  for (int kk = 0; kk < BD; kk += 32) {
    f16x8 b = *(const f16x8*)&memh[(size_t)(w * 16 + lr) * BD + kk + lk * 8];
    #pragma unroll
    for (int m = 0; m < 2; ++m) {
      const int row = m * 16 + lr;
      const int ch = (kk >> 3) + lk;
      f16x8 a = *(const f16x8*)&As[row * BD + ((ch ^ (row & 7)) << 3)];
      acc[m] = __builtin_amdgcn_mfma_f32_16x16x32_f16(a, b, acc[m], 0, 0, 0);
    }
  }
  float local = 0.0f;
  const int mm = w * 16 + lr;                  // C/D: col = lane&15
  if (mm < 50) {
    const float mn = mn2[mm];
    #pragma unroll
    for (int m = 0; m < 2; ++m) {
      #pragma unroll
      for (int j = 0; j < 4; ++j) {
        const int row = m * 16 + lk * 4 + j;   // C/D: row = (lane>>4)*4 + j
        float d = xn[row] - 2.0f * acc[m][j] + mn;
        local += sqrtf(fmaxf(d, 0.0f));
      }
    }
  }
  #pragma unroll
  for (int off = 32; off; off >>= 1) local += __shfl_down(local, off, 64);
  if (l == 0) red[w] = local;
  __syncthreads();
  if (t == 0) atomicAdd(novS, red[0] + red[1] + red[2] + red[3]);
}

// ---------------- GEMM: out = relu(A @ W^T + bias), 64x128 tile, BK=64, 3-buffer ring ----------------
// PICK: 0 = proj (also writes novelty final); 1 = ops_W[idx_a]; 2 = ops_W[idx_b]
template <int PICK, int OUTF16>
__global__ __launch_bounds__(256, 2) void gemm_relu_kernel(
    const f16* __restrict__ A, const f16* __restrict__ Wall,
    const float* __restrict__ ball, const float* __restrict__ logits,
    void* __restrict__ Out, const float* __restrict__ novS,
    float* __restrict__ novOut) {
  __shared__ __align__(16) f16 As[3][4096];   // 3 x 8 KB  (64 rows x 64 f16)
  __shared__ __align__(16) f16 Bs[3][8192];   // 3 x 16 KB (128 rows x 64 f16)

  const int t = threadIdx.x;
  const int l = t & 63;
  const int w = t >> 6;
  const int wr = w >> 1, wc = w & 1;          // wave tile: rows wr*32, cols wc*64
  const int lr = l & 15, lk = l >> 4;

  if (PICK == 0 && blockIdx.x == 0 && blockIdx.y == 0 && t == 0)
    novOut[0] = fminf(1.5f, novS[0] * (1.0f / (8192.0f * 50.0f)));

  int widx = 0;
  if (PICK > 0) {
    float l0 = logits[0], l1 = logits[1], l2 = logits[2];
    int ia = 0; float ba = l0;
    if (l1 > ba) { ba = l1; ia = 1; }
    if (l2 > ba) { ba = l2; ia = 2; }
    if (PICK == 1) {
      widx = ia;
    } else {
      int ib = 0; float bb2 = -3.4e38f;
      if (ia != 0 && l0 > bb2) { bb2 = l0; ib = 0; }
      if (ia != 1 && l1 > bb2) { bb2 = l1; ib = 1; }
      if (ia != 2 && l2 > bb2) { bb2 = l2; ib = 2; }
      widx = ib;
    }
  }
  const f16* W = Wall + (size_t)widx * BD * BD;
  const float* bias = ball + widx * BD;

  const int rowBase = blockIdx.x * 64;
  const int colBase = blockIdx.y * 128;

  f32x4 acc[2][4];
  #pragma unroll
  for (int m = 0; m < 2; ++m)
    #pragma unroll
    for (int n = 0; n < 4; ++n) acc[m][n] = (f32x4){0.f, 0.f, 0.f, 0.f};

  // stage one K-tile (kt) into ring buffer buf: A 8 KB (2 loads/thr), B 16 KB (4 loads/thr)
  auto stage = [&](int buf, int kt) {
    #pragma unroll
    for (int i = 0; i < 2; ++i) {
      const int o = i * 4096 + t * 16;        // byte offset in A tile
      const int row = o >> 7;                 // 128 B per row
      const int sch = ((o >> 4) & 7) ^ (row & 7);
      llds16(A + (size_t)(rowBase + row) * BD + kt + sch * 8,
             &As[buf][(i * 4096 + w * 1024) / 2]);
    }
    #pragma unroll
    for (int i = 0; i < 4; ++i) {
      const int o = i * 4096 + t * 16;        // byte offset in B tile
      const int row = o >> 7;
      const int sch = ((o >> 4) & 7) ^ (row & 7);
      llds16(W + (size_t)(colBase + row) * BD + kt + sch * 8,
             &Bs[buf][(i * 4096 + w * 1024) / 2]);
    }
  };

  auto compute = [&](int buf) {
    #pragma unroll
    for (int kk = 0; kk < 64; kk += 32) {
      f16x8 af[2], bf[4];
      #pragma unroll
      for (int m = 0; m < 2; ++m) {
        const int row = wr * 32 + m * 16 + lr;
        const int ch = (kk >> 3) + lk;
        af[m] = *(const f16x8*)&As[buf][row * 64 + ((ch ^ (row & 7)) << 3)];
      }
      #pragma unroll
      for (int n = 0; n < 4; ++n) {
        const int row = wc * 64 + n * 16 + lr;
        const int ch = (kk >> 3) + lk;
        bf[n] = *(const f16x8*)&Bs[buf][row * 64 + ((ch ^ (row & 7)) << 3)];
      }
      #pragma unroll
      for (int m = 0; m < 2; ++m)
        #pragma unroll
        for (int n = 0; n < 4; ++n)
          acc[m][n] = __builtin_amdgcn_mfma_f32_16x16x32_f16(af[m], bf[n], acc[m][n], 0, 0, 0);
    }
  };

  // prologue: 2 tiles in flight
  stage(0, 0);
  stage(1, 64);
  #pragma unroll
  for (int t8 = 0; t8 < 8; ++t8) {
    if (t8 < 6) stage((t8 + 2) % 3, (t8 + 2) * 64);
    if (t8 <= 5)      asm volatile("s_waitcnt vmcnt(12)" ::: "memory");
    else if (t8 == 6) asm volatile("s_waitcnt vmcnt(6)" ::: "memory");
    else              asm volatile("s_waitcnt vmcnt(0)" ::: "memory");
    __builtin_amdgcn_s_barrier();             // all waves' tile-t loads landed
    compute(t8 % 3);
    __builtin_amdgcn_s_barrier();             // all waves done reading tile t
  }

  // epilogue: bias + relu, store
  #pragma unroll
  for (int n = 0; n < 4; ++n) {
    const int col = colBase + wc * 64 + n * 16 + lr;
    const float bb = bias[col];
    #pragma unroll
    for (int m = 0; m < 2; ++m) {
      #pragma unroll
      for (int j = 0; j < 4; ++j) {
        const int rowg = rowBase + wr * 32 + m * 16 + lk * 4 + j;
        float v = acc[m][n][j] + bb;
        v = fmaxf(v, 0.0f);
        if (OUTF16)
          ((f16*)Out)[(size_t)rowg * BD + col] = (f16)v;
        else
          ((float*)Out)[(size_t)rowg * BD + col] = v;
      }
    }
  }
}

extern "C" void kernel_launch(void* const* d_in, const int* in_sizes, int n_in,
                              void* d_out, int out_size, void* d_ws, size_t ws_size,
                              hipStream_t stream) {
  const float* x      = (const float*)d_in[0];   // [8192,512]
  const float* memf   = (const float*)d_in[1];   // [50,512]
  const float* logits = (const float*)d_in[2];   // [3]
  const float* projW  = (const float*)d_in[3];   // [512,512]
  const float* projB  = (const float*)d_in[4];   // [512]
  const float* opsW   = (const float*)d_in[5];   // [3,512,512]
  const float* opsB   = (const float*)d_in[6];   // [3,512]
  float* out = (float*)d_out;                    // [8192*512 + 1]

  char* ws = (char*)d_ws;
  f16*   xh   = (f16*)(ws);                  // 8 MB   (x f16; reused as h1 output of gemm2)
  f16*   g0   = (f16*)(ws + 8388608);        // 8 MB
  f16*   wh   = (f16*)(ws + 16777216);       // 2 MB: proj_W f16, then ops_W f16
  f16*   memh = (f16*)(ws + 18874368);       // 64 KB (64x512, zero-padded)
  float* mn2  = (float*)(ws + 18972672);     // 256 B
  float* novS = (float*)(ws + 18972928);     // 4 B

  prep_kernel<<<1040, 256, 0, stream>>>(projW, opsW, memf, wh, memh, mn2, novS);
  conv_nov_kernel<<<256, 256, 0, stream>>>(x, memh, mn2, xh, novS);

  // g0 = relu(x @ projW^T + projB); also writes novelty scalar
  gemm_relu_kernel<0, 1><<<dim3(128, 4), 256, 0, stream>>>(
      xh, wh, projB, logits, (void*)g0, novS, out + 4194304);
  // h1 = relu(g0 @ Wa^T + ba)   (overwrites xh)
  gemm_relu_kernel<1, 1><<<dim3(128, 4), 256, 0, stream>>>(
      g0, wh + 262144, opsB, logits, (void*)xh, novS, out + 4194304);
  // out = relu(h1 @ Wb^T + bb)
  gemm_relu_kernel<2, 0><<<dim3(128, 4), 256, 0, stream>>>(
      xh, wh + 262144, opsB, logits, (void*)out, novS, out + 4194304);
}

// Round 4
// 47.397 us; speedup vs baseline: 1.4722x; 1.0471x over previous
//
#include <hip/hip_runtime.h>
#include <hip/hip_bf16.h>

typedef _Float16 f16;
typedef _Float16 f16x8 __attribute__((ext_vector_type(8)));
typedef float f32x4 __attribute__((ext_vector_type(4)));

#define BD 512  // D == H == 512

// async global->LDS, 16B per lane. LDS dest is wave-uniform base + lane*16.
__device__ __forceinline__ void llds16(const f16* g, f16* l) {
  __builtin_amdgcn_global_load_lds(
      (const __attribute__((address_space(1))) unsigned int*)g,
      (__attribute__((address_space(3))) unsigned int*)l,
      16, 0, 0);
}

// ---- fused: weight cvt + x cvt + row norms + novelty partials (256 blocks) ----
__global__ __launch_bounds__(256) void conv_nov_w_kernel(
    const float* __restrict__ x, const float* __restrict__ memf,
    const float* __restrict__ projW, const float* __restrict__ opsW,
    f16* __restrict__ wh, f16* __restrict__ xh,
    float* __restrict__ novPart) {
  __shared__ __align__(16) f16 As[32 * BD];   // 32 KB, chunk-swizzled
  __shared__ float xn[32];
  __shared__ float red[4];
  const int t = threadIdx.x, l = t & 63, w = t >> 6;
  const int rbase = blockIdx.x * 32;

  // weights: 1,048,576 f16 total = 256 blocks * 256 thr * 16 each (16 | 262144)
  {
    const int e = (blockIdx.x * 256 + t) * 16;
    const float* s = (e < 262144) ? (projW + e) : (opsW + (e - 262144));
    float4 v0 = ((const float4*)s)[0];
    float4 v1 = ((const float4*)s)[1];
    float4 v2 = ((const float4*)s)[2];
    float4 v3 = ((const float4*)s)[3];
    f16x8 h0, h1;
    h0[0]=(f16)v0.x; h0[1]=(f16)v0.y; h0[2]=(f16)v0.z; h0[3]=(f16)v0.w;
    h0[4]=(f16)v1.x; h0[5]=(f16)v1.y; h0[6]=(f16)v1.z; h0[7]=(f16)v1.w;
    h1[0]=(f16)v2.x; h1[1]=(f16)v2.y; h1[2]=(f16)v2.z; h1[3]=(f16)v2.w;
    h1[4]=(f16)v3.x; h1[5]=(f16)v3.y; h1[6]=(f16)v3.z; h1[7]=(f16)v3.w;
    *(f16x8*)&wh[e] = h0;
    *(f16x8*)&wh[e + 8] = h1;
  }

  // phase 1: convert rows w*8..w*8+7; lane l covers cols l*8..l*8+7
  #pragma unroll
  for (int rr = 0; rr < 8; ++rr) {
    const int r = w * 8 + rr;
    const float* src = x + (size_t)(rbase + r) * BD + l * 8;
    float4 v0 = *(const float4*)src;
    float4 v1 = *(const float4*)(src + 4);
    f16x8 h;
    h[0]=(f16)v0.x; h[1]=(f16)v0.y; h[2]=(f16)v0.z; h[3]=(f16)v0.w;
    h[4]=(f16)v1.x; h[5]=(f16)v1.y; h[6]=(f16)v1.z; h[7]=(f16)v1.w;
    *(f16x8*)&xh[(size_t)(rbase + r) * BD + l * 8] = h;
    const int cs = l ^ (r & 7);               // chunk swizzle (low 3 bits)
    *(f16x8*)&As[r * BD + cs * 8] = h;
    float ss = v0.x*v0.x + v0.y*v0.y + v0.z*v0.z + v0.w*v0.w
             + v1.x*v1.x + v1.y*v1.y + v1.z*v1.z + v1.w*v1.w;
    #pragma unroll
    for (int off = 32; off; off >>= 1) ss += __shfl_down(ss, off, 64);
    if (l == 0) xn[r] = ss;
  }
  __syncthreads();

  // phase 2: wave w handles mem rows w*16..+15 (f16-converted in regs), x rows 0..31
  const int lr = l & 15, lk = l >> 4;
  const int mm = w * 16 + lr;
  f32x4 acc0 = (f32x4){0.f, 0.f, 0.f, 0.f};
  f32x4 acc1 = (f32x4){0.f, 0.f, 0.f, 0.f};
  float msq = 0.f;
  #pragma unroll
  for (int kk = 0; kk < BD; kk += 32) {
    f16x8 bfr;
    if (mm < 50) {
      const float* ms = memf + (size_t)mm * BD + kk + lk * 8;
      float4 v0 = ((const float4*)ms)[0];
      float4 v1 = ((const float4*)ms)[1];
      bfr[0]=(f16)v0.x; bfr[1]=(f16)v0.y; bfr[2]=(f16)v0.z; bfr[3]=(f16)v0.w;
      bfr[4]=(f16)v1.x; bfr[5]=(f16)v1.y; bfr[6]=(f16)v1.z; bfr[7]=(f16)v1.w;
      msq += v0.x*v0.x + v0.y*v0.y + v0.z*v0.z + v0.w*v0.w
           + v1.x*v1.x + v1.y*v1.y + v1.z*v1.z + v1.w*v1.w;
    } else {
      #pragma unroll
      for (int j = 0; j < 8; ++j) bfr[j] = (f16)0.f;
    }
    const int ch = (kk >> 3) + lk;
    {
      const int row0 = lr;
      f16x8 a0 = *(const f16x8*)&As[row0 * BD + ((ch ^ (row0 & 7)) << 3)];
      acc0 = __builtin_amdgcn_mfma_f32_16x16x32_f16(a0, bfr, acc0, 0, 0, 0);
      const int row1 = 16 + lr;
      f16x8 a1 = *(const f16x8*)&As[row1 * BD + ((ch ^ (row1 & 7)) << 3)];
      acc1 = __builtin_amdgcn_mfma_f32_16x16x32_f16(a1, bfr, acc1, 0, 0, 0);
    }
  }
  float local = 0.f;
  if (mm < 50) {
    #pragma unroll
    for (int j = 0; j < 4; ++j) {
      const int r0 = lk * 4 + j;             // C/D: row = (lane>>4)*4 + j
      float d0 = xn[r0] - 2.f * acc0[j] + msq;
      local += sqrtf(fmaxf(d0, 0.f));
      float d1 = xn[16 + r0] - 2.f * acc1[j] + msq;
      local += sqrtf(fmaxf(d1, 0.f));
    }
  }
  #pragma unroll
  for (int off = 32; off; off >>= 1) local += __shfl_down(local, off, 64);
  if (l == 0) red[w] = local;
  __syncthreads();
  if (t == 0) novPart[blockIdx.x] = red[0] + red[1] + red[2] + red[3];
}

// ---- GEMM: out = relu(A @ W^T + bias), 64x128 tile, BK=64, 3-buffer ring, 1 barrier/step ----
// PICK: 0 = proj (also finalizes novelty); 1 = ops_W[idx_a]; 2 = ops_W[idx_b]
template <int PICK, int OUTF16>
__global__ __launch_bounds__(256, 2) void gemm_relu_kernel(
    const f16* __restrict__ A, const f16* __restrict__ Wall,
    const float* __restrict__ ball, const float* __restrict__ logits,
    void* __restrict__ Out, const float* __restrict__ novPart,
    float* __restrict__ novOut) {
  __shared__ __align__(16) char lds[3 * 24576];  // per buf: 8 KB A + 16 KB B

  const int t = threadIdx.x;
  const int l = t & 63;
  const int w = t >> 6;
  const int wr = w >> 1, wc = w & 1;          // wave tile: rows wr*32, cols wc*64
  const int lr = l & 15, lk = l >> 4;

  if (PICK == 0 && blockIdx.x == 0 && blockIdx.y == 0 && w == 0) {
    float s = novPart[l] + novPart[l + 64] + novPart[l + 128] + novPart[l + 192];
    #pragma unroll
    for (int off = 32; off; off >>= 1) s += __shfl_down(s, off, 64);
    if (l == 0) novOut[0] = fminf(1.5f, s * (1.0f / (8192.0f * 50.0f)));
  }

  int widx = 0;
  if (PICK > 0) {
    float l0 = logits[0], l1 = logits[1], l2 = logits[2];
    int ia = 0; float ba = l0;
    if (l1 > ba) { ba = l1; ia = 1; }
    if (l2 > ba) { ba = l2; ia = 2; }
    if (PICK == 1) {
      widx = ia;
    } else {
      int ib = 0; float bb2 = -3.4e38f;
      if (ia != 0)             { bb2 = l0; ib = 0; }
      if (ia != 1 && l1 > bb2) { bb2 = l1; ib = 1; }
      if (ia != 2 && l2 > bb2) { bb2 = l2; ib = 2; }
      widx = ib;
    }
  }
  const f16* W = Wall + (size_t)widx * BD * BD;
  const float* bias = ball + widx * BD;

  const int rowBase = blockIdx.x * 64;
  const int colBase = blockIdx.y * 128;

  f32x4 acc[2][4];
  #pragma unroll
  for (int m = 0; m < 2; ++m)
    #pragma unroll
    for (int n = 0; n < 4; ++n) acc[m][n] = (f32x4){0.f, 0.f, 0.f, 0.f};

  // stage one K-tile into ring buffer buf: A 8 KB (2 loads/thr), B 16 KB (4 loads/thr)
  auto stage = [&](int buf, int kt) {
    f16* Ab = (f16*)(lds + buf * 24576);
    f16* Bb = (f16*)(lds + buf * 24576 + 8192);
    #pragma unroll
    for (int i = 0; i < 2; ++i) {
      const int o = i * 4096 + t * 16;       // byte offset in 8 KB A tile
      const int row = o >> 7;                // 128 B per row (64 f16)
      const int sch = ((o >> 4) & 7) ^ (row & 7);
      llds16(A + (size_t)(rowBase + row) * BD + kt + sch * 8,
             Ab + (i * 4096 + w * 1024) / 2);
    }
    #pragma unroll
    for (int i = 0; i < 4; ++i) {
      const int o = i * 4096 + t * 16;       // byte offset in 16 KB B tile
      const int row = o >> 7;
      const int sch = ((o >> 4) & 7) ^ (row & 7);
      llds16(W + (size_t)(colBase + row) * BD + kt + sch * 8,
             Bb + (i * 4096 + w * 1024) / 2);
    }
  };

  auto compute = [&](int buf) {
    const f16* Ab = (const f16*)(lds + buf * 24576);
    const f16* Bb = (const f16*)(lds + buf * 24576 + 8192);
    #pragma unroll
    for (int kk = 0; kk < 64; kk += 32) {
      f16x8 af[2], bf[4];
      #pragma unroll
      for (int m = 0; m < 2; ++m) {
        const int row = wr * 32 + m * 16 + lr;
        const int ch = (kk >> 3) + lk;
        af[m] = *(const f16x8*)&Ab[row * 64 + ((ch ^ (row & 7)) << 3)];
      }
      #pragma unroll
      for (int n = 0; n < 4; ++n) {
        const int row = wc * 64 + n * 16 + lr;
        const int ch = (kk >> 3) + lk;
        bf[n] = *(const f16x8*)&Bb[row * 64 + ((ch ^ (row & 7)) << 3)];
      }
      __builtin_amdgcn_s_setprio(1);
      #pragma unroll
      for (int m = 0; m < 2; ++m)
        #pragma unroll
        for (int n = 0; n < 4; ++n)
          acc[m][n] = __builtin_amdgcn_mfma_f32_16x16x32_f16(af[m], bf[n], acc[m][n], 0, 0, 0);
      __builtin_amdgcn_s_setprio(0);
    }
  };

  // 3-deep ring, ONE barrier per K-step, counted vmcnt (never 0 mid-loop).
  // stage(t+2) overwrites buf[(t-1)%3]; safe because lgkmcnt(0) at end of step
  // t-1 drained its ds_reads and the barrier orders all waves.
  stage(0, 0);
  stage(1, 64);
  #pragma unroll
  for (int t8 = 0; t8 < 8; ++t8) {
    if (t8 < 7) asm volatile("s_waitcnt vmcnt(6)" ::: "memory");
    else        asm volatile("s_waitcnt vmcnt(0)" ::: "memory");
    __builtin_amdgcn_s_barrier();            // tile t8 fully in LDS (all waves)
    if (t8 < 6) stage((t8 + 2) % 3, (t8 + 2) * 64);
    compute(t8 % 3);
    asm volatile("s_waitcnt lgkmcnt(0)" ::: "memory");  // ds_reads drained
  }

  // epilogue: bias + relu, store
  #pragma unroll
  for (int n = 0; n < 4; ++n) {
    const int col = colBase + wc * 64 + n * 16 + lr;
    const float bbv = bias[col];
    #pragma unroll
    for (int m = 0; m < 2; ++m) {
      #pragma unroll
      for (int j = 0; j < 4; ++j) {
        const int rowg = rowBase + wr * 32 + m * 16 + lk * 4 + j;
        float v = fmaxf(acc[m][n][j] + bbv, 0.f);
        if (OUTF16) ((f16*)Out)[(size_t)rowg * BD + col] = (f16)v;
        else        ((float*)Out)[(size_t)rowg * BD + col] = v;
      }
    }
  }
}

extern "C" void kernel_launch(void* const* d_in, const int* in_sizes, int n_in,
                              void* d_out, int out_size, void* d_ws, size_t ws_size,
                              hipStream_t stream) {
  const float* x      = (const float*)d_in[0];   // [8192,512]
  const float* memf   = (const float*)d_in[1];   // [50,512]
  const float* logits = (const float*)d_in[2];   // [3]
  const float* projW  = (const float*)d_in[3];   // [512,512]
  const float* projB  = (const float*)d_in[4];   // [512]
  const float* opsW   = (const float*)d_in[5];   // [3,512,512]
  const float* opsB   = (const float*)d_in[6];   // [3,512]
  float* out = (float*)d_out;                    // [8192*512 + 1]

  char* ws = (char*)d_ws;
  f16*   xh      = (f16*)(ws);               // 8 MB (x f16; reused as h1)
  f16*   g0      = (f16*)(ws + 8388608);     // 8 MB
  f16*   wh      = (f16*)(ws + 16777216);    // 2 MB: proj_W f16, then ops_W f16
  float* novPart = (float*)(ws + 18874368);  // 1 KB (256 floats)

  conv_nov_w_kernel<<<256, 256, 0, stream>>>(x, memf, projW, opsW, wh, xh, novPart);

  // g0 = relu(xh @ projW^T + projB); also finalizes novelty scalar
  gemm_relu_kernel<0, 1><<<dim3(128, 4), 256, 0, stream>>>(
      xh, wh, projB, logits, (void*)g0, novPart, out + 4194304);
  // h1 = relu(g0 @ Wa^T + ba)   (overwrites xh)
  gemm_relu_kernel<1, 1><<<dim3(128, 4), 256, 0, stream>>>(
      g0, wh + 262144, opsB, logits, (void*)xh, novPart, out + 4194304);
  // out = relu(h1 @ Wb^T + bb)  (fp32 out)
  gemm_relu_kernel<2, 0><<<dim3(128, 4), 256, 0, stream>>>(
      xh, wh + 262144, opsB, logits, (void*)out, novPart, out + 4194304);
}